// Round 3
// baseline (661.600 us; speedup 1.0000x reference)
//
#include <hip/hip_runtime.h>
#include <hip/hip_bf16.h>

typedef __attribute__((ext_vector_type(8))) short short8;
typedef __attribute__((ext_vector_type(4))) float floatx4;
typedef __attribute__((ext_vector_type(16))) float floatx16;

#define N_SEQ 8192
#define M_ROWS 32768   // 4*8192

__device__ __forceinline__ unsigned short f2bf(float f) {
    unsigned int x = __builtin_bit_cast(unsigned int, f);
    x += 0x7fff + ((x >> 16) & 1);   // RNE
    return (unsigned short)(x >> 16);
}

// ---------------------------------------------------------------------------
// Kernel 0: transpose+convert 9 weight matrices [256k x 256n] fp32 -> bf16 Wt[job][n][k]
__global__ __launch_bounds__(256) void transpose_w(
    const float* __restrict__ Wq, const float* __restrict__ Wk,
    const float* __restrict__ Wv, unsigned short* __restrict__ Wt)
{
    int job = blockIdx.x;
    int k = blockIdx.y;
    int n = threadIdx.x;
    const float* src =
        (job < 3) ? (Wq + job * 65536) :
        (job < 6) ? (Wk + (job - 3) * 65536) :
                    (Wv + (job - 6) * 65536);
    Wt[(size_t)job * 65536 + n * 256 + k] = f2bf(src[k * 256 + n]);
}

// ---------------------------------------------------------------------------
// Kernel 1: Q projection for 3 branches. q = (f1+p1)@Wq[j] + bq[j], then
// exp() -> expQ[32768][768] bf16 (col offset j*256); column sums -> S[4][768] fp32.
__global__ __launch_bounds__(256) void projq_kernel(
    const float* __restrict__ f1, const float* __restrict__ p1,
    const float* __restrict__ bq, const unsigned short* __restrict__ Wt,
    unsigned short* __restrict__ expQ, float* __restrict__ S)
{
    __shared__ __align__(16) unsigned short As[128][72];
    int j = blockIdx.z;              // branch 0..2
    int m0 = blockIdx.x * 128;       // global row
    int n0 = blockIdx.y * 128;
    int tid = threadIdx.x;
    const unsigned short* Wj = Wt + (size_t)j * 65536;
    const float* bias = bq + j * 256;
    int coloff = j * 256;

    int lane = tid & 63, wave = tid >> 6;
    int wm = wave >> 1, wn = wave & 1;
    int quad = lane >> 4, l15 = lane & 15;

    floatx4 acc[4][4];
    #pragma unroll
    for (int a = 0; a < 4; a++)
        #pragma unroll
        for (int c = 0; c < 4; c++)
            #pragma unroll
            for (int r = 0; r < 4; r++) acc[a][c][r] = 0.0f;

    for (int kt = 0; kt < 4; kt++) {
        __syncthreads();
        #pragma unroll
        for (int p = 0; p < 4; p++) {
            int r = (tid >> 3) + p * 32;
            int kc = (tid & 7) * 8;
            size_t ga = (size_t)(m0 + r) * 256 + kt * 64 + kc;
            float4 x0 = *(const float4*)(f1 + ga);
            float4 x1 = *(const float4*)(f1 + ga + 4);
            float4 y0 = *(const float4*)(p1 + ga);
            float4 y1 = *(const float4*)(p1 + ga + 4);
            short8 v;
            v[0] = (short)f2bf(x0.x + y0.x); v[1] = (short)f2bf(x0.y + y0.y);
            v[2] = (short)f2bf(x0.z + y0.z); v[3] = (short)f2bf(x0.w + y0.w);
            v[4] = (short)f2bf(x1.x + y1.x); v[5] = (short)f2bf(x1.y + y1.y);
            v[6] = (short)f2bf(x1.z + y1.z); v[7] = (short)f2bf(x1.w + y1.w);
            *(short8*)&As[r][kc] = v;
        }
        __syncthreads();
        #pragma unroll
        for (int kc = 0; kc < 64; kc += 32) {
            short8 af[4], bfr[4];
            #pragma unroll
            for (int sm = 0; sm < 4; sm++)
                af[sm] = *(const short8*)&As[wm * 64 + sm * 16 + l15][kc + quad * 8];
            #pragma unroll
            for (int sn = 0; sn < 4; sn++) {
                int ncol = n0 + wn * 64 + sn * 16 + l15;
                bfr[sn] = *(const short8*)(Wj + (size_t)ncol * 256 + kt * 64 + kc + quad * 8);
            }
            #pragma unroll
            for (int sm = 0; sm < 4; sm++)
                #pragma unroll
                for (int sn = 0; sn < 4; sn++)
                    acc[sm][sn] = __builtin_amdgcn_mfma_f32_16x16x32_bf16(
                        af[sm], bfr[sn], acc[sm][sn], 0, 0, 0);
        }
    }

    int b = m0 >> 13;
    float bb[4];
    #pragma unroll
    for (int sn = 0; sn < 4; sn++) bb[sn] = bias[n0 + wn * 64 + sn * 16 + l15];

    float colsum[4] = {0.f, 0.f, 0.f, 0.f};
    #pragma unroll
    for (int sm = 0; sm < 4; sm++)
        #pragma unroll
        for (int sn = 0; sn < 4; sn++)
            #pragma unroll
            for (int r = 0; r < 4; r++) {
                float e = __expf(acc[sm][sn][r] + bb[sn]);
                colsum[sn] += e;
                int row = m0 + wm * 64 + sm * 16 + quad * 4 + r;
                int col = coloff + n0 + wn * 64 + sn * 16 + l15;
                expQ[(size_t)row * 768 + col] = f2bf(e);
            }
    #pragma unroll
    for (int sn = 0; sn < 4; sn++) {
        float v = colsum[sn];
        v += __shfl_xor(v, 16, 64);
        v += __shfl_xor(v, 32, 64);
        if (quad == 0)
            atomicAdd(&S[b * 768 + coloff + n0 + wn * 64 + sn * 16 + l15], v);
    }
}

// ---------------------------------------------------------------------------
// Kernel 2: K or V projection for ONE (branch, batch): [8192x256]@[256x256].
// z=0: K = (fin+pin)@Wtk + bk_i, per-head (32-ch) softmax -> Kb (bf16)
// z=1: V = fin@Wtv + bv_i -> Vbb (bf16)
__global__ __launch_bounds__(256) void projkv_kernel(
    const float* __restrict__ fin, const float* __restrict__ pin,
    const float* __restrict__ bki, const float* __restrict__ bvi,
    const unsigned short* __restrict__ Wtk, const unsigned short* __restrict__ Wtv,
    unsigned short* __restrict__ Kb, unsigned short* __restrict__ Vbb)
{
    __shared__ __align__(16) unsigned short As[128][72];
    int isV = blockIdx.z;
    int m0 = blockIdx.x * 128;       // local row within batch
    int n0 = blockIdx.y * 128;
    int tid = threadIdx.x;
    const unsigned short* Wj = isV ? Wtv : Wtk;
    const float* bias = isV ? bvi : bki;
    unsigned short* outp = isV ? Vbb : Kb;

    int lane = tid & 63, wave = tid >> 6;
    int wm = wave >> 1, wn = wave & 1;
    int quad = lane >> 4, l15 = lane & 15;

    floatx4 acc[4][4];
    #pragma unroll
    for (int a = 0; a < 4; a++)
        #pragma unroll
        for (int c = 0; c < 4; c++)
            #pragma unroll
            for (int r = 0; r < 4; r++) acc[a][c][r] = 0.0f;

    for (int kt = 0; kt < 4; kt++) {
        __syncthreads();
        #pragma unroll
        for (int p = 0; p < 4; p++) {
            int r = (tid >> 3) + p * 32;
            int kc = (tid & 7) * 8;
            size_t ga = (size_t)(m0 + r) * 256 + kt * 64 + kc;
            float4 x0 = *(const float4*)(fin + ga);
            float4 x1 = *(const float4*)(fin + ga + 4);
            if (!isV) {
                float4 y0 = *(const float4*)(pin + ga);
                float4 y1 = *(const float4*)(pin + ga + 4);
                x0.x += y0.x; x0.y += y0.y; x0.z += y0.z; x0.w += y0.w;
                x1.x += y1.x; x1.y += y1.y; x1.z += y1.z; x1.w += y1.w;
            }
            short8 v;
            v[0] = (short)f2bf(x0.x); v[1] = (short)f2bf(x0.y);
            v[2] = (short)f2bf(x0.z); v[3] = (short)f2bf(x0.w);
            v[4] = (short)f2bf(x1.x); v[5] = (short)f2bf(x1.y);
            v[6] = (short)f2bf(x1.z); v[7] = (short)f2bf(x1.w);
            *(short8*)&As[r][kc] = v;
        }
        __syncthreads();
        #pragma unroll
        for (int kc = 0; kc < 64; kc += 32) {
            short8 af[4], bfr[4];
            #pragma unroll
            for (int sm = 0; sm < 4; sm++)
                af[sm] = *(const short8*)&As[wm * 64 + sm * 16 + l15][kc + quad * 8];
            #pragma unroll
            for (int sn = 0; sn < 4; sn++) {
                int ncol = n0 + wn * 64 + sn * 16 + l15;
                bfr[sn] = *(const short8*)(Wj + (size_t)ncol * 256 + kt * 64 + kc + quad * 8);
            }
            #pragma unroll
            for (int sm = 0; sm < 4; sm++)
                #pragma unroll
                for (int sn = 0; sn < 4; sn++)
                    acc[sm][sn] = __builtin_amdgcn_mfma_f32_16x16x32_bf16(
                        af[sm], bfr[sn], acc[sm][sn], 0, 0, 0);
        }
    }

    float bb[4];
    #pragma unroll
    for (int sn = 0; sn < 4; sn++) bb[sn] = bias[n0 + wn * 64 + sn * 16 + l15];

    if (!isV) {
        float ex[4][4][4];
        #pragma unroll
        for (int sm = 0; sm < 4; sm++)
            #pragma unroll
            for (int sn = 0; sn < 4; sn++)
                #pragma unroll
                for (int r = 0; r < 4; r++)
                    ex[sm][sn][r] = __expf(acc[sm][sn][r] + bb[sn]);
        // per-row softmax over each 32-channel head: heads = col pairs (sn0,sn1),(sn2,sn3)
        #pragma unroll
        for (int sm = 0; sm < 4; sm++)
            #pragma unroll
            for (int r = 0; r < 4; r++) {
                float t0 = ex[sm][0][r] + ex[sm][1][r];
                t0 += __shfl_xor(t0, 1, 64);
                t0 += __shfl_xor(t0, 2, 64);
                t0 += __shfl_xor(t0, 4, 64);
                t0 += __shfl_xor(t0, 8, 64);
                float i0 = 1.0f / t0;
                ex[sm][0][r] *= i0; ex[sm][1][r] *= i0;
                float t1 = ex[sm][2][r] + ex[sm][3][r];
                t1 += __shfl_xor(t1, 1, 64);
                t1 += __shfl_xor(t1, 2, 64);
                t1 += __shfl_xor(t1, 4, 64);
                t1 += __shfl_xor(t1, 8, 64);
                float i1 = 1.0f / t1;
                ex[sm][2][r] *= i1; ex[sm][3][r] *= i1;
            }
        #pragma unroll
        for (int sm = 0; sm < 4; sm++)
            #pragma unroll
            for (int sn = 0; sn < 4; sn++)
                #pragma unroll
                for (int r = 0; r < 4; r++) {
                    int row = m0 + wm * 64 + sm * 16 + quad * 4 + r;
                    int col = n0 + wn * 64 + sn * 16 + l15;
                    outp[(size_t)row * 256 + col] = f2bf(ex[sm][sn][r]);
                }
    } else {
        #pragma unroll
        for (int sm = 0; sm < 4; sm++)
            #pragma unroll
            for (int sn = 0; sn < 4; sn++)
                #pragma unroll
                for (int r = 0; r < 4; r++) {
                    int row = m0 + wm * 64 + sm * 16 + quad * 4 + r;
                    int col = n0 + wn * 64 + sn * 16 + l15;
                    outp[(size_t)row * 256 + col] = f2bf(acc[sm][sn][r] + bb[sn]);
                }
    }
}

// ---------------------------------------------------------------------------
// Kernel 3: ctx partial for one (branch,batch): ctxg[h][c][d] += sum_n Kb[n][h*32+c]*Vbb[n][h*32+d]
// grid 256: blockIdx.x = h*32 + slice (32 slices of 256 rows each)
__global__ __launch_bounds__(256) void ctx_kernel(
    const unsigned short* __restrict__ Kb, const unsigned short* __restrict__ Vbb,
    float* __restrict__ ctxg)
{
    __shared__ float red[4][1024];
    int h = blockIdx.x >> 5;
    int slice = blockIdx.x & 31;
    int tid = threadIdx.x;
    int lane = tid & 63, wave = tid >> 6;
    int half = lane >> 5, cd = lane & 31;

    const unsigned short* Kp = Kb  + h * 32 + cd;
    const unsigned short* Vp = Vbb + h * 32 + cd;

    floatx16 acc;
    #pragma unroll
    for (int q = 0; q < 16; q++) acc[q] = 0.0f;

    int rbase = slice * 256 + wave * 64 + half * 8;
    #pragma unroll
    for (int it = 0; it < 4; it++) {
        int r = rbase + it * 16;
        const unsigned short* kp = Kp + (size_t)r * 256;
        const unsigned short* vp = Vp + (size_t)r * 256;
        short8 af, bfr;
        #pragma unroll
        for (int e = 0; e < 8; e++) {
            af[e]  = (short)kp[e * 256];
            bfr[e] = (short)vp[e * 256];
        }
        acc = __builtin_amdgcn_mfma_f32_32x32x16_bf16(af, bfr, acc, 0, 0, 0);
    }
    #pragma unroll
    for (int reg = 0; reg < 16; reg++) {
        int c = (reg & 3) + 8 * (reg >> 2) + 4 * half;
        red[wave][c * 32 + cd] = acc[reg];
    }
    __syncthreads();
    #pragma unroll
    for (int q = 0; q < 4; q++) {
        int idx = tid + q * 256;
        float s = red[0][idx] + red[1][idx] + red[2][idx] + red[3][idx];
        atomicAdd(&ctxg[(size_t)h * 1024 + idx], s);
    }
}

// ---------------------------------------------------------------------------
// Kernel 4: Wtld[b][e][i*256+h*32+c] = sum_d (ctx[g][c][d]/S[b][i*256+h*32+c]) * Wrp[i*256+h*32+d][e]
__global__ __launch_bounds__(256) void wtilde_kernel(
    const float* __restrict__ ctx, const float* __restrict__ S,
    const float* __restrict__ Wrp, unsigned short* __restrict__ Wtld)
{
    __shared__ float cp[1024];
    int g = blockIdx.x;  // i*32 + b*8 + h
    int i = g >> 5, b = (g >> 3) & 3, h = g & 7;
    int t = threadIdx.x;
    #pragma unroll
    for (int q = 0; q < 4; q++) {
        int idx = t + q * 256;
        int c = idx >> 5;
        cp[idx] = ctx[(size_t)g * 1024 + idx] / S[b * 768 + i * 256 + h * 32 + c];
    }
    __syncthreads();
    float accv[32];
    #pragma unroll
    for (int c = 0; c < 32; c++) accv[c] = 0.0f;
    for (int d = 0; d < 32; d++) {
        float w = Wrp[(size_t)(i * 256 + h * 32 + d) * 256 + t];
        #pragma unroll
        for (int c = 0; c < 32; c++) accv[c] += cp[c * 32 + d] * w;
    }
    for (int c = 0; c < 32; c++)
        Wtld[((size_t)b * 256 + t) * 768 + i * 256 + h * 32 + c] = f2bf(accv[c]);
}

// ---------------------------------------------------------------------------
// Kernel 5: out[b] = expQ[b] ([8192x768] bf16) @ Wtld[b]^T ([256][768] bf16) + brp -> fp32
__global__ __launch_bounds__(256) void out_kernel(
    const unsigned short* __restrict__ expQ, const unsigned short* __restrict__ Wtld,
    const float* __restrict__ brp, float* __restrict__ outp)
{
    __shared__ __align__(16) unsigned short As[128][72];
    int m0 = blockIdx.x * 128;
    int n0 = blockIdx.y * 128;
    int b = m0 >> 13;
    const unsigned short* Wb = Wtld + (size_t)b * 256 * 768;
    int tid = threadIdx.x;
    int lane = tid & 63, wave = tid >> 6;
    int wm = wave >> 1, wn = wave & 1;
    int quad = lane >> 4, l15 = lane & 15;

    floatx4 acc[4][4];
    #pragma unroll
    for (int a = 0; a < 4; a++)
        #pragma unroll
        for (int c = 0; c < 4; c++)
            #pragma unroll
            for (int r = 0; r < 4; r++) acc[a][c][r] = 0.0f;

    for (int kt = 0; kt < 12; kt++) {
        __syncthreads();
        #pragma unroll
        for (int p = 0; p < 4; p++) {
            int r = (tid >> 3) + p * 32;
            int kc = (tid & 7) * 8;
            size_t ga = (size_t)(m0 + r) * 768 + kt * 64 + kc;
            *(short8*)&As[r][kc] = *(const short8*)(expQ + ga);
        }
        __syncthreads();
        #pragma unroll
        for (int kc = 0; kc < 64; kc += 32) {
            short8 af[4], bfr[4];
            #pragma unroll
            for (int sm = 0; sm < 4; sm++)
                af[sm] = *(const short8*)&As[wm * 64 + sm * 16 + l15][kc + quad * 8];
            #pragma unroll
            for (int sn = 0; sn < 4; sn++) {
                int ncol = n0 + wn * 64 + sn * 16 + l15;
                bfr[sn] = *(const short8*)(Wb + (size_t)ncol * 768 + kt * 64 + kc + quad * 8);
            }
            #pragma unroll
            for (int sm = 0; sm < 4; sm++)
                #pragma unroll
                for (int sn = 0; sn < 4; sn++)
                    acc[sm][sn] = __builtin_amdgcn_mfma_f32_16x16x32_bf16(
                        af[sm], bfr[sn], acc[sm][sn], 0, 0, 0);
        }
    }

    float bb[4];
    #pragma unroll
    for (int sn = 0; sn < 4; sn++) bb[sn] = brp[n0 + wn * 64 + sn * 16 + l15];
    #pragma unroll
    for (int sm = 0; sm < 4; sm++)
        #pragma unroll
        for (int sn = 0; sn < 4; sn++)
            #pragma unroll
            for (int r = 0; r < 4; r++) {
                int row = m0 + wm * 64 + sm * 16 + quad * 4 + r;
                int col = n0 + wn * 64 + sn * 16 + l15;
                outp[(size_t)row * 256 + col] = acc[sm][sn][r] + bb[sn];
            }
}

// ---------------------------------------------------------------------------
extern "C" void kernel_launch(void* const* d_in, const int* in_sizes, int n_in,
                              void* d_out, int out_size, void* d_ws, size_t ws_size,
                              hipStream_t stream)
{
    (void)in_sizes; (void)n_in; (void)out_size; (void)ws_size;
    const float* f1  = (const float*)d_in[0];
    const float* f2  = (const float*)d_in[1];
    const float* f3  = (const float*)d_in[2];
    const float* f4  = (const float*)d_in[3];
    const float* p1  = (const float*)d_in[4];
    const float* p2  = (const float*)d_in[5];
    const float* p3  = (const float*)d_in[6];
    const float* p4  = (const float*)d_in[7];
    const float* Wq  = (const float*)d_in[8];
    const float* bq  = (const float*)d_in[9];
    const float* Wk  = (const float*)d_in[10];
    const float* bk  = (const float*)d_in[11];
    const float* Wv  = (const float*)d_in[12];
    const float* bv  = (const float*)d_in[13];
    const float* Wrp = (const float*)d_in[14];
    const float* brp = (const float*)d_in[15];

    // workspace layout (total 61,878,272 B ~= 59 MB)
    char* ws = (char*)d_ws;
    unsigned short* expQ = (unsigned short*)(ws);                 // 50,331,648
    unsigned short* Kb   = (unsigned short*)(ws + 50331648);      //  4,194,304
    unsigned short* Vbb  = (unsigned short*)(ws + 54525952);      //  4,194,304
    unsigned short* Wt   = (unsigned short*)(ws + 58720256);      //  1,179,648
    unsigned short* Wtld = (unsigned short*)(ws + 59899904);      //  1,572,864
    float*          ctx  = (float*)(ws + 61472768);               //    393,216
    float*          S    = (float*)(ws + 61865984);               //     12,288

    hipMemsetAsync(ctx, 0, 393216 + 12288, stream);  // ctx + S contiguous

    transpose_w<<<dim3(9, 256), 256, 0, stream>>>(Wq, Wk, Wv, Wt);

    projq_kernel<<<dim3(256, 2, 3), 256, 0, stream>>>(f1, p1, bq, Wt, expQ, S);

    const float* fins[3] = {f2, f3, f4};
    const float* pins[3] = {p2, p3, p4};
    for (int i = 0; i < 3; i++) {
        for (int b = 0; b < 4; b++) {
            const float* fin = fins[i] + (size_t)b * N_SEQ * 256;
            const float* pin = pins[i] + (size_t)b * N_SEQ * 256;
            projkv_kernel<<<dim3(64, 2, 2), 256, 0, stream>>>(
                fin, pin, bk + i * 256, bv + i * 256,
                Wt + (size_t)(3 + i) * 65536, Wt + (size_t)(6 + i) * 65536, Kb, Vbb);
            ctx_kernel<<<dim3(256), 256, 0, stream>>>(
                Kb, Vbb, ctx + (size_t)(i * 32 + b * 8) * 1024);
        }
    }

    wtilde_kernel<<<dim3(96), 256, 0, stream>>>(ctx, S, Wrp, Wtld);
    out_kernel<<<dim3(256, 2), 256, 0, stream>>>(expQ, Wtld, brp, (float*)d_out);
}

// Round 4
// 483.581 us; speedup vs baseline: 1.3681x; 1.3681x over previous
//
#include <hip/hip_runtime.h>
#include <hip/hip_bf16.h>

typedef __attribute__((ext_vector_type(8))) short short8;
typedef __attribute__((ext_vector_type(4))) float floatx4;
typedef __attribute__((ext_vector_type(16))) float floatx16;

#define N_SEQ 8192
#define M_ROWS 32768   // 4*8192

__device__ __forceinline__ unsigned short f2bf(float f) {
    unsigned int x = __builtin_bit_cast(unsigned int, f);
    x += 0x7fff + ((x >> 16) & 1);   // RNE
    return (unsigned short)(x >> 16);
}

// ---------------------------------------------------------------------------
// Kernel 0: transpose+convert 9 weight matrices [256k x 256n] fp32 -> bf16 Wt[job][n][k]
__global__ __launch_bounds__(256) void transpose_w(
    const float* __restrict__ Wq, const float* __restrict__ Wk,
    const float* __restrict__ Wv, unsigned short* __restrict__ Wt)
{
    int job = blockIdx.x;
    int k = blockIdx.y;
    int n = threadIdx.x;
    const float* src =
        (job < 3) ? (Wq + job * 65536) :
        (job < 6) ? (Wk + (job - 3) * 65536) :
                    (Wv + (job - 6) * 65536);
    Wt[(size_t)job * 65536 + n * 256 + k] = f2bf(src[k * 256 + n]);
}

// ---------------------------------------------------------------------------
// Kernel 1: Q projection, all 3 branches per block. A = bf16(f1+p1) staged in
// LDS once (64 rows x 256 k), then 6 n-tiles (3 branches x 128) computed
// against it. exp -> expQ bf16 [32768][768]; column sums -> S[4][768] fp32.
__global__ __launch_bounds__(256) void projq_kernel(
    const float* __restrict__ f1, const float* __restrict__ p1,
    const float* __restrict__ bq, const unsigned short* __restrict__ Wt,
    unsigned short* __restrict__ expQ, float* __restrict__ S)
{
    __shared__ __align__(16) unsigned short As[64][264];
    int m0 = blockIdx.x * 64;
    int b = m0 >> 13;
    int tid = threadIdx.x;
    int lane = tid & 63, wave = tid >> 6;
    int wm = wave >> 1, wn = wave & 1;
    int quad = lane >> 4, l15 = lane & 15;

    // stage A = bf16(f1 + p1)
    {
        int row = tid >> 2, seg = tid & 3;
        const float* fr = f1 + (size_t)(m0 + row) * 256 + seg * 64;
        const float* pr = p1 + (size_t)(m0 + row) * 256 + seg * 64;
        #pragma unroll
        for (int q = 0; q < 8; q++) {
            float4 x0 = *(const float4*)(fr + q * 8);
            float4 x1 = *(const float4*)(fr + q * 8 + 4);
            float4 y0 = *(const float4*)(pr + q * 8);
            float4 y1 = *(const float4*)(pr + q * 8 + 4);
            short8 v;
            v[0] = (short)f2bf(x0.x + y0.x); v[1] = (short)f2bf(x0.y + y0.y);
            v[2] = (short)f2bf(x0.z + y0.z); v[3] = (short)f2bf(x0.w + y0.w);
            v[4] = (short)f2bf(x1.x + y1.x); v[5] = (short)f2bf(x1.y + y1.y);
            v[6] = (short)f2bf(x1.z + y1.z); v[7] = (short)f2bf(x1.w + y1.w);
            *(short8*)&As[row][seg * 64 + q * 8] = v;
        }
    }
    __syncthreads();

    for (int nj = 0; nj < 6; nj++) {
        int j = nj >> 1;
        int n0 = (nj & 1) * 128;
        const unsigned short* Wj = Wt + (size_t)j * 65536;

        floatx4 acc[2][4];
        #pragma unroll
        for (int sm = 0; sm < 2; sm++)
            #pragma unroll
            for (int sn = 0; sn < 4; sn++)
                #pragma unroll
                for (int r = 0; r < 4; r++) acc[sm][sn][r] = 0.0f;

        #pragma unroll
        for (int ks = 0; ks < 8; ks++) {
            short8 af[2], bfr[4];
            #pragma unroll
            for (int sm = 0; sm < 2; sm++)
                af[sm] = *(const short8*)&As[wm * 32 + sm * 16 + l15][ks * 32 + quad * 8];
            #pragma unroll
            for (int sn = 0; sn < 4; sn++) {
                int ncol = n0 + wn * 64 + sn * 16 + l15;
                bfr[sn] = *(const short8*)(Wj + (size_t)ncol * 256 + ks * 32 + quad * 8);
            }
            #pragma unroll
            for (int sm = 0; sm < 2; sm++)
                #pragma unroll
                for (int sn = 0; sn < 4; sn++)
                    acc[sm][sn] = __builtin_amdgcn_mfma_f32_16x16x32_bf16(
                        af[sm], bfr[sn], acc[sm][sn], 0, 0, 0);
        }

        float colsum[4] = {0.f, 0.f, 0.f, 0.f};
        #pragma unroll
        for (int sm = 0; sm < 2; sm++)
            #pragma unroll
            for (int sn = 0; sn < 4; sn++) {
                float bb = bq[j * 256 + n0 + wn * 64 + sn * 16 + l15];
                #pragma unroll
                for (int r = 0; r < 4; r++) {
                    float e = __expf(acc[sm][sn][r] + bb);
                    colsum[sn] += e;
                    int row = m0 + wm * 32 + sm * 16 + quad * 4 + r;
                    int col = j * 256 + n0 + wn * 64 + sn * 16 + l15;
                    expQ[(size_t)row * 768 + col] = f2bf(e);
                }
            }
        #pragma unroll
        for (int sn = 0; sn < 4; sn++) {
            float v = colsum[sn];
            v += __shfl_xor(v, 16, 64);
            v += __shfl_xor(v, 32, 64);
            if (quad == 0)
                atomicAdd(&S[b * 768 + j * 256 + n0 + wn * 64 + sn * 16 + l15], v);
        }
    }
}

// ---------------------------------------------------------------------------
// Kernel 2: fused K/V projection + softmax(K) + ctx accumulation.
// Grid: 384 = 12 (i,b) x 32 chunks; each block does 4 m-tiles of 64 rows.
// Per m-tile: K = (f+p)@Wk+bk -> per-head row softmax -> LDS; V = f@Wv+bv -> LDS;
// ctx[h] += K_s^T @ V_s (per-wave 32x32 MFMA, 2 heads/wave), regs across tiles,
// one fp32 atomicAdd set per block at the end.
__global__ __launch_bounds__(256) void projkv_ctx(
    const float* __restrict__ f2, const float* __restrict__ f3, const float* __restrict__ f4,
    const float* __restrict__ p2, const float* __restrict__ p3, const float* __restrict__ p4,
    const float* __restrict__ bk, const float* __restrict__ bv,
    const unsigned short* __restrict__ Wt, float* __restrict__ ctx)
{
    __shared__ __align__(16) unsigned short Ak[64][264];
    __shared__ __align__(16) unsigned short Av[64][264];

    int blk = blockIdx.x;
    int c = blk & 31;
    int ib = blk >> 5;
    int b = ib & 3, i = ib >> 2;
    const float* fin = ((i == 0) ? f2 : (i == 1) ? f3 : f4) + (size_t)b * N_SEQ * 256;
    const float* pin = ((i == 0) ? p2 : (i == 1) ? p3 : p4) + (size_t)b * N_SEQ * 256;
    const unsigned short* Wk_ = Wt + (size_t)(3 + i) * 65536;
    const unsigned short* Wv_ = Wt + (size_t)(6 + i) * 65536;

    int tid = threadIdx.x;
    int lane = tid & 63, wn = tid >> 6;     // 4 waves over 4 col-slices of 64
    int quad = lane >> 4, l15 = lane & 15;
    int srow = tid >> 2, seg = tid & 3;     // staging assignment

    float bkk[4], bvv[4];
    #pragma unroll
    for (int sn = 0; sn < 4; sn++) {
        bkk[sn] = bk[i * 256 + wn * 64 + sn * 16 + l15];
        bvv[sn] = bv[i * 256 + wn * 64 + sn * 16 + l15];
    }

    floatx16 ctxacc[2];
    #pragma unroll
    for (int e = 0; e < 2; e++)
        #pragma unroll
        for (int q = 0; q < 16; q++) ctxacc[e][q] = 0.0f;

    for (int t = 0; t < 4; t++) {
        int m0 = (c + t * 32) * 64;
        __syncthreads();   // protect previous tile's K_s/V_s reads
        // stage A_k = bf16(f+p), A_v = bf16(f)
        {
            const float* fr = fin + (size_t)(m0 + srow) * 256 + seg * 64;
            const float* pr = pin + (size_t)(m0 + srow) * 256 + seg * 64;
            #pragma unroll
            for (int q = 0; q < 8; q++) {
                float4 x0 = *(const float4*)(fr + q * 8);
                float4 x1 = *(const float4*)(fr + q * 8 + 4);
                float4 y0 = *(const float4*)(pr + q * 8);
                float4 y1 = *(const float4*)(pr + q * 8 + 4);
                short8 vv, kk;
                vv[0] = (short)f2bf(x0.x); kk[0] = (short)f2bf(x0.x + y0.x);
                vv[1] = (short)f2bf(x0.y); kk[1] = (short)f2bf(x0.y + y0.y);
                vv[2] = (short)f2bf(x0.z); kk[2] = (short)f2bf(x0.z + y0.z);
                vv[3] = (short)f2bf(x0.w); kk[3] = (short)f2bf(x0.w + y0.w);
                vv[4] = (short)f2bf(x1.x); kk[4] = (short)f2bf(x1.x + y1.x);
                vv[5] = (short)f2bf(x1.y); kk[5] = (short)f2bf(x1.y + y1.y);
                vv[6] = (short)f2bf(x1.z); kk[6] = (short)f2bf(x1.z + y1.z);
                vv[7] = (short)f2bf(x1.w); kk[7] = (short)f2bf(x1.w + y1.w);
                *(short8*)&Av[srow][seg * 64 + q * 8] = vv;
                *(short8*)&Ak[srow][seg * 64 + q * 8] = kk;
            }
        }
        __syncthreads();

        // ---- K GEMM: 64 x 64 per wave (full 64 rows, cols wn*64..+63)
        floatx4 acc[4][4];
        #pragma unroll
        for (int sm = 0; sm < 4; sm++)
            #pragma unroll
            for (int sn = 0; sn < 4; sn++)
                #pragma unroll
                for (int r = 0; r < 4; r++) acc[sm][sn][r] = 0.0f;
        #pragma unroll
        for (int ks = 0; ks < 8; ks++) {
            short8 af[4], bfr[4];
            #pragma unroll
            for (int sm = 0; sm < 4; sm++)
                af[sm] = *(const short8*)&Ak[sm * 16 + l15][ks * 32 + quad * 8];
            #pragma unroll
            for (int sn = 0; sn < 4; sn++) {
                int ncol = wn * 64 + sn * 16 + l15;
                bfr[sn] = *(const short8*)(Wk_ + (size_t)ncol * 256 + ks * 32 + quad * 8);
            }
            #pragma unroll
            for (int sm = 0; sm < 4; sm++)
                #pragma unroll
                for (int sn = 0; sn < 4; sn++)
                    acc[sm][sn] = __builtin_amdgcn_mfma_f32_16x16x32_bf16(
                        af[sm], bfr[sn], acc[sm][sn], 0, 0, 0);
        }
        // per-row softmax over each head (32 cols = sn pairs (0,1),(2,3))
        #pragma unroll
        for (int sm = 0; sm < 4; sm++)
            #pragma unroll
            for (int sn = 0; sn < 4; sn++)
                #pragma unroll
                for (int r = 0; r < 4; r++)
                    acc[sm][sn][r] = __expf(acc[sm][sn][r] + bkk[sn]);
        #pragma unroll
        for (int sm = 0; sm < 4; sm++)
            #pragma unroll
            for (int r = 0; r < 4; r++) {
                float t0 = acc[sm][0][r] + acc[sm][1][r];
                t0 += __shfl_xor(t0, 1, 64);
                t0 += __shfl_xor(t0, 2, 64);
                t0 += __shfl_xor(t0, 4, 64);
                t0 += __shfl_xor(t0, 8, 64);
                float i0 = 1.0f / t0;
                acc[sm][0][r] *= i0; acc[sm][1][r] *= i0;
                float t1 = acc[sm][2][r] + acc[sm][3][r];
                t1 += __shfl_xor(t1, 1, 64);
                t1 += __shfl_xor(t1, 2, 64);
                t1 += __shfl_xor(t1, 4, 64);
                t1 += __shfl_xor(t1, 8, 64);
                float i1 = 1.0f / t1;
                acc[sm][2][r] *= i1; acc[sm][3][r] *= i1;
            }
        __syncthreads();   // everyone done reading Ak
        // park K_s into Ak's slot
        #pragma unroll
        for (int sm = 0; sm < 4; sm++)
            #pragma unroll
            for (int sn = 0; sn < 4; sn++)
                #pragma unroll
                for (int r = 0; r < 4; r++)
                    Ak[sm * 16 + quad * 4 + r][wn * 64 + sn * 16 + l15] = f2bf(acc[sm][sn][r]);

        // ---- V GEMM (Av still intact)
        #pragma unroll
        for (int sm = 0; sm < 4; sm++)
            #pragma unroll
            for (int sn = 0; sn < 4; sn++)
                #pragma unroll
                for (int r = 0; r < 4; r++) acc[sm][sn][r] = 0.0f;
        #pragma unroll
        for (int ks = 0; ks < 8; ks++) {
            short8 af[4], bfr[4];
            #pragma unroll
            for (int sm = 0; sm < 4; sm++)
                af[sm] = *(const short8*)&Av[sm * 16 + l15][ks * 32 + quad * 8];
            #pragma unroll
            for (int sn = 0; sn < 4; sn++) {
                int ncol = wn * 64 + sn * 16 + l15;
                bfr[sn] = *(const short8*)(Wv_ + (size_t)ncol * 256 + ks * 32 + quad * 8);
            }
            #pragma unroll
            for (int sm = 0; sm < 4; sm++)
                #pragma unroll
                for (int sn = 0; sn < 4; sn++)
                    acc[sm][sn] = __builtin_amdgcn_mfma_f32_16x16x32_bf16(
                        af[sm], bfr[sn], acc[sm][sn], 0, 0, 0);
        }
        __syncthreads();   // done reading Av; K_s writes drained
        #pragma unroll
        for (int sm = 0; sm < 4; sm++)
            #pragma unroll
            for (int sn = 0; sn < 4; sn++)
                #pragma unroll
                for (int r = 0; r < 4; r++)
                    Av[sm * 16 + quad * 4 + r][wn * 64 + sn * 16 + l15] =
                        f2bf(acc[sm][sn][r] + bvv[sn]);
        __syncthreads();

        // ---- ctx: heads h = wn*2 + e; D[c][d] += sum_n K_s[n][h*32+c] * V_s[n][h*32+d]
        #pragma unroll
        for (int e = 0; e < 2; e++) {
            int hc = (wn * 2 + e) * 32 + (lane & 31);
            #pragma unroll
            for (int s = 0; s < 4; s++) {
                short8 afr, bfr2;
                #pragma unroll
                for (int jj = 0; jj < 8; jj++) {
                    int n = s * 16 + (lane >> 5) * 8 + jj;
                    afr[jj]  = (short)Ak[n][hc];
                    bfr2[jj] = (short)Av[n][hc];
                }
                ctxacc[e] = __builtin_amdgcn_mfma_f32_32x32x16_bf16(afr, bfr2, ctxacc[e], 0, 0, 0);
            }
        }
    }

    // final accumulation to global ctx
    #pragma unroll
    for (int e = 0; e < 2; e++) {
        int h = wn * 2 + e;
        int g = i * 32 + b * 8 + h;
        int d = lane & 31;
        #pragma unroll
        for (int reg = 0; reg < 16; reg++) {
            int cc = (reg & 3) + 8 * (reg >> 2) + 4 * (lane >> 5);
            atomicAdd(&ctx[(size_t)g * 1024 + cc * 32 + d], ctxacc[e][reg]);
        }
    }
}

// ---------------------------------------------------------------------------
// Kernel 3: Wtld[b][e][i*256+h*32+c] = sum_d (ctx[g][c][d]/S[b][i*256+h*32+c]) * Wrp[i*256+h*32+d][e]
__global__ __launch_bounds__(256) void wtilde_kernel(
    const float* __restrict__ ctx, const float* __restrict__ S,
    const float* __restrict__ Wrp, unsigned short* __restrict__ Wtld)
{
    __shared__ float cp[1024];
    int g = blockIdx.x;  // i*32 + b*8 + h
    int i = g >> 5, b = (g >> 3) & 3, h = g & 7;
    int t = threadIdx.x;
    #pragma unroll
    for (int q = 0; q < 4; q++) {
        int idx = t + q * 256;
        int c = idx >> 5;
        cp[idx] = ctx[(size_t)g * 1024 + idx] / S[b * 768 + i * 256 + h * 32 + c];
    }
    __syncthreads();
    float accv[32];
    #pragma unroll
    for (int c = 0; c < 32; c++) accv[c] = 0.0f;
    for (int d = 0; d < 32; d++) {
        float w = Wrp[(size_t)(i * 256 + h * 32 + d) * 256 + t];
        #pragma unroll
        for (int c = 0; c < 32; c++) accv[c] += cp[c * 32 + d] * w;
    }
    for (int c = 0; c < 32; c++)
        Wtld[((size_t)b * 256 + t) * 768 + i * 256 + h * 32 + c] = f2bf(accv[c]);
}

// ---------------------------------------------------------------------------
// Kernel 4: out[b] = expQ[b] ([8192x768] bf16) @ Wtld[b]^T ([256][768] bf16) + brp -> fp32
__global__ __launch_bounds__(256) void out_kernel(
    const unsigned short* __restrict__ expQ, const unsigned short* __restrict__ Wtld,
    const float* __restrict__ brp, float* __restrict__ outp)
{
    __shared__ __align__(16) unsigned short As[128][72];
    int m0 = blockIdx.x * 128;
    int n0 = blockIdx.y * 128;
    int b = m0 >> 13;
    const unsigned short* Wb = Wtld + (size_t)b * 256 * 768;
    int tid = threadIdx.x;
    int lane = tid & 63, wave = tid >> 6;
    int wm = wave >> 1, wn = wave & 1;
    int quad = lane >> 4, l15 = lane & 15;

    floatx4 acc[4][4];
    #pragma unroll
    for (int a = 0; a < 4; a++)
        #pragma unroll
        for (int cc = 0; cc < 4; cc++)
            #pragma unroll
            for (int r = 0; r < 4; r++) acc[a][cc][r] = 0.0f;

    for (int kt = 0; kt < 12; kt++) {
        __syncthreads();
        #pragma unroll
        for (int p = 0; p < 4; p++) {
            int r = (tid >> 3) + p * 32;
            int kc = (tid & 7) * 8;
            size_t ga = (size_t)(m0 + r) * 768 + kt * 64 + kc;
            *(short8*)&As[r][kc] = *(const short8*)(expQ + ga);
        }
        __syncthreads();
        #pragma unroll
        for (int kc = 0; kc < 64; kc += 32) {
            short8 af[4], bfr[4];
            #pragma unroll
            for (int sm = 0; sm < 4; sm++)
                af[sm] = *(const short8*)&As[wm * 64 + sm * 16 + l15][kc + quad * 8];
            #pragma unroll
            for (int sn = 0; sn < 4; sn++) {
                int ncol = n0 + wn * 64 + sn * 16 + l15;
                bfr[sn] = *(const short8*)(Wb + (size_t)ncol * 768 + kt * 64 + kc + quad * 8);
            }
            #pragma unroll
            for (int sm = 0; sm < 4; sm++)
                #pragma unroll
                for (int sn = 0; sn < 4; sn++)
                    acc[sm][sn] = __builtin_amdgcn_mfma_f32_16x16x32_bf16(
                        af[sm], bfr[sn], acc[sm][sn], 0, 0, 0);
        }
    }

    float bb[4];
    #pragma unroll
    for (int sn = 0; sn < 4; sn++) bb[sn] = brp[n0 + wn * 64 + sn * 16 + l15];
    #pragma unroll
    for (int sm = 0; sm < 4; sm++)
        #pragma unroll
        for (int sn = 0; sn < 4; sn++)
            #pragma unroll
            for (int r = 0; r < 4; r++) {
                int row = m0 + wm * 64 + sm * 16 + quad * 4 + r;
                int col = n0 + wn * 64 + sn * 16 + l15;
                outp[(size_t)row * 256 + col] = acc[sm][sn][r] + bb[sn];
            }
}

// ---------------------------------------------------------------------------
extern "C" void kernel_launch(void* const* d_in, const int* in_sizes, int n_in,
                              void* d_out, int out_size, void* d_ws, size_t ws_size,
                              hipStream_t stream)
{
    (void)in_sizes; (void)n_in; (void)out_size; (void)ws_size;
    const float* f1  = (const float*)d_in[0];
    const float* f2  = (const float*)d_in[1];
    const float* f3  = (const float*)d_in[2];
    const float* f4  = (const float*)d_in[3];
    const float* p1  = (const float*)d_in[4];
    const float* p2  = (const float*)d_in[5];
    const float* p3  = (const float*)d_in[6];
    const float* p4  = (const float*)d_in[7];
    const float* Wq  = (const float*)d_in[8];
    const float* bq  = (const float*)d_in[9];
    const float* Wk  = (const float*)d_in[10];
    const float* bk  = (const float*)d_in[11];
    const float* Wv  = (const float*)d_in[12];
    const float* bv  = (const float*)d_in[13];
    const float* Wrp = (const float*)d_in[14];
    const float* brp = (const float*)d_in[15];

    // workspace layout (total ~52 MB)
    char* ws = (char*)d_ws;
    unsigned short* expQ = (unsigned short*)(ws);                 // 50,331,648
    unsigned short* Wt   = (unsigned short*)(ws + 50331648);      //  1,179,648
    unsigned short* Wtld = (unsigned short*)(ws + 51511296);      //  1,572,864
    float*          ctx  = (float*)(ws + 53084160);               //    393,216
    float*          S    = (float*)(ws + 53477376);               //     12,288

    hipMemsetAsync(ctx, 0, 393216 + 12288, stream);  // ctx + S contiguous

    transpose_w<<<dim3(9, 256), 256, 0, stream>>>(Wq, Wk, Wv, Wt);
    projq_kernel<<<dim3(512), 256, 0, stream>>>(f1, p1, bq, Wt, expQ, S);
    projkv_ctx<<<dim3(384), 256, 0, stream>>>(f2, f3, f4, p2, p3, p4, bk, bv, Wt, ctx);
    wtilde_kernel<<<dim3(96), 256, 0, stream>>>(ctx, S, Wrp, Wtld);
    out_kernel<<<dim3(256, 2), 256, 0, stream>>>(expQ, Wtld, brp, (float*)d_out);
}